// Round 1
// 379.976 us; speedup vs baseline: 1.0252x; 1.0252x over previous
//
#include <hip/hip_runtime.h>
#include <hip/hip_bf16.h>

// GNN_LinearAttn: B=8, N=2048, D=512, fp32 in/out, bf16 MFMA internally.
//
// Pipeline:
//  K0 castw:   Wqk/Wl/Wr fp32 -> bf16
//  K1 gate:    deg=rowsum(adj); xg = x * sigmoid(deg*Wd + bd)      (bf16)
//  K2 transp:  xgT[b,d,n] = xg[b,n,d]                              (bf16)
//  K3 gemm8:   QK = sigmoid(xg @ Wqk^T + bqk)                      (bf16)
//  K4 gemm:    S  = (QK @ QK^T)/sqrt(D) * adj; denom += rowsum(S)  (bf16)
//              -- SYMMETRIC: only 136 upper-tri block pairs computed
//  K5 gemm8:   h  = (S @ xgT^T) / (denom+1e-6)                     (bf16)
//  K6 gemm8:   out = relu(h @ Wl^T + bl + xg @ Wr^T)               (fp32)
//
// gemm8 core (K3/K5/K6): BM=256 x BN=128, BK=64, 8 waves (4Mx2N), each wave
// a 64x64 sub-tile (4x4 frags of 16x16x32 bf16 MFMA). TRIPLE-buffered LDS
// (3 x 48KB = 144KB dynamic): tile t computed from buf A while t+1 resident
// in buf B and t+2 in flight to buf C -> boundary wait is s_waitcnt vmcnt(6),
// never 0 in the main loop (T3+T4). s_setprio(1) around the MFMA cluster
// (T5). XOR-chunk swizzle on LDS (T2) identical to the verified old core.
// Grid = exactly 256 blocks (1/CU) for all three gemm8 kernels.
//
// K4 keeps the old 128x128/4-wave core (dual-side symmetric epilogue).

typedef __bf16 bf16;
typedef __bf16 bf16x2 __attribute__((ext_vector_type(2)));
typedef __bf16 bf16x8 __attribute__((ext_vector_type(8)));
typedef float  f32x4  __attribute__((ext_vector_type(4)));

#define Bb 8
#define Nn 2048
#define Dd 512
#define SMEM_BYTES 33792     // K4: max(As+Bs=32768, epilogue 64*132*4=33792)
#define TILE8_BYTES 49152    // gemm8: A 256x64x2 (32KB) + B 128x64x2 (16KB)
#define SMEM8_BYTES (3 * TILE8_BYTES)   // 147456

__device__ __forceinline__ bf16 to_bf16(float f) { return (bf16)f; }
__device__ __forceinline__ float sigmoidf_(float x) { return 1.0f / (1.0f + __expf(-x)); }

__device__ __forceinline__ void gld16(const void* g, void* l) {
    __builtin_amdgcn_global_load_lds(
        (__attribute__((address_space(1))) void*)(void*)g,
        (__attribute__((address_space(3))) void*)l,
        16, 0, 0);
}

// ---------------- old 128x128 4-wave core (K4 only) ----------------
__device__ __forceinline__ void gemm_bt_core(
    const bf16* __restrict__ A, const bf16* __restrict__ Bt,
    int lda, int ldb, int K,
    char* As, char* Bs, f32x4 acc[4][4])
{
    const int tid  = threadIdx.x;
    const int lane = tid & 63;
    const int wave = tid >> 6;
    const int wm = (wave >> 1) << 6;
    const int wn = (wave & 1) << 6;

    for (int kt = 0; kt < K; kt += 64) {
#pragma unroll
        for (int i = 0; i < 4; ++i) {
            int ff   = i * 256 + tid;
            int row  = ff >> 3;
            int slot = ff & 7;
            int gch  = slot ^ (row & 7);
            gld16(A  + (size_t)row * lda + kt + gch * 8, As + ff * 16);
            gld16(Bt + (size_t)row * ldb + kt + gch * 8, Bs + ff * 16);
        }
        __syncthreads();
#pragma unroll
        for (int ks = 0; ks < 2; ++ks) {
            bf16x8 af[4], bfr[4];
#pragma unroll
            for (int mi = 0; mi < 4; ++mi) {
                int row  = wm + mi * 16 + (lane & 15);
                int slot = ((ks << 2) + (lane >> 4)) ^ (row & 7);
                af[mi] = *(const bf16x8*)(As + row * 128 + slot * 16);
            }
#pragma unroll
            for (int ni = 0; ni < 4; ++ni) {
                int row  = wn + ni * 16 + (lane & 15);
                int slot = ((ks << 2) + (lane >> 4)) ^ (row & 7);
                bfr[ni] = *(const bf16x8*)(Bs + row * 128 + slot * 16);
            }
#pragma unroll
            for (int mi = 0; mi < 4; ++mi)
#pragma unroll
                for (int ni = 0; ni < 4; ++ni)
                    acc[mi][ni] = __builtin_amdgcn_mfma_f32_16x16x32_bf16(
                        af[mi], bfr[ni], acc[mi][ni], 0, 0, 0);
        }
        __syncthreads();
    }
}

#define GEMM_PROLOGUE()                                  \
    __shared__ __align__(16) char smem[SMEM_BYTES];      \
    char* As = smem;                                     \
    char* Bs = smem + 16384;                             \
    f32x4 acc[4][4];                                     \
    _Pragma("unroll") for (int mi = 0; mi < 4; ++mi)     \
    _Pragma("unroll") for (int ni = 0; ni < 4; ++ni)     \
        acc[mi][ni] = (f32x4){0.f, 0.f, 0.f, 0.f};

// ---------------- new 256x128 8-wave deep-pipelined core ----------------
// Invariant at top of tile t: bA holds tile t (complete), bB holds tile t+1
// (its 6 loads/thread are the ONLY outstanding VMEM, <=6), bC free.
// During tile t: issue tile t+2 -> bC (3 gld per sub-phase). At tile end:
// vmcnt(6) retires tile t+1's loads (oldest 6 of <=12), barrier, rotate.
__device__ __forceinline__ void gemm_bt8_core(
    const bf16* __restrict__ A, const bf16* __restrict__ Bt,
    int lda, int ldb, int K, char* smem, f32x4 acc[4][4])
{
    const int tid  = threadIdx.x;          // 0..511
    const int lane = tid & 63;
    const int wave = tid >> 6;             // 0..7
    const int wm = (wave >> 1) << 6;       // 0,64,128,192
    const int wn = (wave & 1) << 6;        // 0,64
    const int NT = K >> 6;                 // K-tiles (>=8 here)

    char* bA = smem;
    char* bB = smem + TILE8_BYTES;
    char* bC = smem + 2 * TILE8_BYTES;

    // stage one half of K-tile t into base: 2 A-chunk loads + 1 B-chunk load
    // per thread. LDS layout: row*128B, phys slot = chunk ^ (row&7) (T2).
    auto stage_half = [&](char* base, int t, int half) {
        const int kt = t << 6;
#pragma unroll
        for (int i = 0; i < 2; ++i) {
            int ff   = (half * 2 + i) * 512 + tid;   // A: 2048 chunks total
            int row  = ff >> 3;                      // 0..255
            int slot = ff & 7;
            int gch  = slot ^ (row & 7);
            gld16(A + (size_t)row * lda + kt + gch * 8, base + ff * 16);
        }
        int ff   = half * 512 + tid;                 // B: 1024 chunks total
        int row  = ff >> 3;                          // 0..127
        int slot = ff & 7;
        int gch  = slot ^ (row & 7);
        gld16(Bt + (size_t)row * ldb + kt + gch * 8, base + 32768 + ff * 16);
    };

    // prologue: tiles 0 and 1 in flight (12 ops), retire tile 0 (vmcnt(6))
    stage_half(bA, 0, 0); stage_half(bA, 0, 1);
    stage_half(bB, 1, 0); stage_half(bB, 1, 1);
    asm volatile("s_waitcnt vmcnt(6)" ::: "memory");
    __builtin_amdgcn_s_barrier();

#pragma unroll 1
    for (int t = 0; t < NT; ++t) {
#pragma unroll
        for (int ks = 0; ks < 2; ++ks) {
            bf16x8 af[4], bfr[4];
#pragma unroll
            for (int mi = 0; mi < 4; ++mi) {
                int row  = wm + mi * 16 + (lane & 15);
                int slot = ((ks << 2) + (lane >> 4)) ^ (row & 7);
                af[mi] = *(const bf16x8*)(bA + row * 128 + slot * 16);
            }
#pragma unroll
            for (int ni = 0; ni < 4; ++ni) {
                int row  = wn + ni * 16 + (lane & 15);
                int slot = ((ks << 2) + (lane >> 4)) ^ (row & 7);
                bfr[ni] = *(const bf16x8*)(bA + 32768 + row * 128 + slot * 16);
            }
            if (t + 2 < NT) stage_half(bC, t + 2, ks);   // uniform branch
            __builtin_amdgcn_s_barrier();
            asm volatile("s_waitcnt lgkmcnt(0)" ::: "memory");
            __builtin_amdgcn_sched_barrier(0);
            __builtin_amdgcn_s_setprio(1);
#pragma unroll
            for (int mi = 0; mi < 4; ++mi)
#pragma unroll
                for (int ni = 0; ni < 4; ++ni)
                    acc[mi][ni] = __builtin_amdgcn_mfma_f32_16x16x32_bf16(
                        af[mi], bfr[ni], acc[mi][ni], 0, 0, 0);
            __builtin_amdgcn_s_setprio(0);
            __builtin_amdgcn_sched_barrier(0);
            if (ks == 1) {
                if (t + 2 < NT)      asm volatile("s_waitcnt vmcnt(6)" ::: "memory");
                else if (t + 1 < NT) asm volatile("s_waitcnt vmcnt(0)" ::: "memory");
            }
            __builtin_amdgcn_s_barrier();
        }
        char* tmp = bA; bA = bB; bB = bC; bC = tmp;
    }
}

// 256-row LDS-roundtrip epilogue: 4 phases of 64 rows, fp32 [64][132].
// Each thread emits 8 contiguous cols of 2 rows per phase.
template <typename F>
__device__ __forceinline__ void epilogue_rt8(f32x4 acc[4][4], char* smem, F&& emit)
{
    const int tid  = threadIdx.x;
    const int lane = tid & 63;
    const int wave = tid >> 6;
    const int wm4 = wave >> 1;           // row-phase owner 0..3
    const int wn  = (wave & 1) << 6;
    const int cq = lane >> 4;
    const int cl = lane & 15;
    float* t = (float*)smem;             // [64][132]
    const int chunk = tid & 15;          // col chunk (8 f32) -> 128 cols
    const int rbase = tid >> 4;          // 0..31
#pragma unroll
    for (int ph = 0; ph < 4; ++ph) {
        __syncthreads();
        if (wm4 == ph) {
#pragma unroll
            for (int mi = 0; mi < 4; ++mi)
#pragma unroll
                for (int ni = 0; ni < 4; ++ni)
#pragma unroll
                    for (int r = 0; r < 4; ++r) {
                        int lr = mi * 16 + cq * 4 + r;
                        int lc = wn + ni * 16 + cl;
                        t[lr * 132 + lc] = acc[mi][ni][r];
                    }
        }
        __syncthreads();
#pragma unroll
        for (int rr = 0; rr < 2; ++rr) {
            int lr = rr * 32 + rbase;
            f32x4 a = *(const f32x4*)&t[lr * 132 + chunk * 8];
            f32x4 b = *(const f32x4*)&t[lr * 132 + chunk * 8 + 4];
            float v[8] = {a[0], a[1], a[2], a[3], b[0], b[1], b[2], b[3]};
            emit(ph * 64 + lr, chunk * 8, v);
        }
    }
}

// ---------------- K0: weight casts ----------------
__global__ __launch_bounds__(256) void k_castw(
    const float* __restrict__ Wqk, const float* __restrict__ Wl,
    const float* __restrict__ Wr,
    bf16* __restrict__ Wqkb, bf16* __restrict__ Wlb, bf16* __restrict__ Wrb)
{
    int i = blockIdx.x * 256 + threadIdx.x;   // 262144 total
    Wqkb[i] = to_bf16(Wqk[i]);
    Wlb[i]  = to_bf16(Wl[i]);
    Wrb[i]  = to_bf16(Wr[i]);
}

// ---------------- K1: deg + gate + xg ----------------
__global__ __launch_bounds__(256) void k_gate(
    const float* __restrict__ x, const float* __restrict__ adj,
    const float* __restrict__ Wd, const float* __restrict__ bd,
    bf16* __restrict__ xg)
{
    const int rowg = blockIdx.x;                   // b*N + n
    const float4* arow = (const float4*)(adj + (size_t)rowg * Nn);
    float4 v0 = arow[threadIdx.x];
    float4 v1 = arow[threadIdx.x + 256];
    float s = v0.x + v0.y + v0.z + v0.w + v1.x + v1.y + v1.z + v1.w;
#pragma unroll
    for (int off = 32; off > 0; off >>= 1) s += __shfl_down(s, off, 64);
    __shared__ float red[4];
    if ((threadIdx.x & 63) == 0) red[threadIdx.x >> 6] = s;
    __syncthreads();
    const float deg = red[0] + red[1] + red[2] + red[3];
    // vectorized gate: thread handles d = 2*tid, 2*tid+1
    const int d2 = threadIdx.x;                    // 0..255, covers 512 cols
    float2 xv  = ((const float2*)(x + (size_t)rowg * Dd))[d2];
    float2 wd  = ((const float2*)Wd)[d2];
    float2 bd2 = ((const float2*)bd)[d2];
    bf16x2 o;
    o[0] = to_bf16(xv.x * sigmoidf_(deg * wd.x + bd2.x));
    o[1] = to_bf16(xv.y * sigmoidf_(deg * wd.y + bd2.y));
    *(bf16x2*)(xg + (size_t)rowg * Dd + d2 * 2) = o;
}

// ---------------- K2: transpose xg -> xgT ----------------
__global__ __launch_bounds__(256) void k_transpose(
    const bf16* __restrict__ xg, bf16* __restrict__ xgT)
{
    const int b = blockIdx.z, nt = blockIdx.y, dt = blockIdx.x;
    __shared__ bf16 tile[64][66];
    const int c = threadIdx.x & 63, r0 = threadIdx.x >> 6;
    const bf16* src = xg + ((size_t)b * Nn + nt * 64) * Dd + dt * 64;
#pragma unroll
    for (int i = 0; i < 16; ++i) {
        int r = i * 4 + r0;
        tile[r][c] = src[(size_t)r * Dd + c];
    }
    __syncthreads();
    bf16* dst = xgT + ((size_t)b * Dd + dt * 64) * Nn + nt * 64;
#pragma unroll
    for (int i = 0; i < 16; ++i) {
        int r = i * 4 + r0;
        dst[(size_t)r * Nn + c] = tile[c][r];
    }
}

// ---------------- K3: QK = sigmoid(xg @ Wqk^T + bqk) [gemm8] ----------------
__global__ __launch_bounds__(512) void k_qk_gemm8(
    const bf16* __restrict__ xg, const bf16* __restrict__ Wqkb,
    const float* __restrict__ bqk, bf16* __restrict__ QK)
{
    extern __shared__ __align__(16) char smem[];
    const int blockRow = blockIdx.y * 256;   // 0..16383 (B*N flattened)
    const int blockCol = blockIdx.x * 128;   // 0..511
    f32x4 acc[4][4];
#pragma unroll
    for (int mi = 0; mi < 4; ++mi)
#pragma unroll
        for (int ni = 0; ni < 4; ++ni) acc[mi][ni] = (f32x4){0.f, 0.f, 0.f, 0.f};
    gemm_bt8_core(xg + (size_t)blockRow * Dd, Wqkb + (size_t)blockCol * Dd,
                  Dd, Dd, Dd, smem, acc);
    epilogue_rt8(acc, smem, [&](int lr, int lc, float* v) {
        int c = blockCol + lc;
        float4 b0 = *(const float4*)(bqk + c);
        float4 b1 = *(const float4*)(bqk + c + 4);
        float bb[8] = {b0.x, b0.y, b0.z, b0.w, b1.x, b1.y, b1.z, b1.w};
        bf16x8 o;
#pragma unroll
        for (int j = 0; j < 8; ++j) o[j] = to_bf16(sigmoidf_(v[j] + bb[j]));
        *(bf16x8*)(QK + (size_t)(blockRow + lr) * Dd + c) = o;
    });
}

// ------- K4: S = (QK @ QK^T) * scale * adj, denom += rowsum(S) -------
__global__ __launch_bounds__(256) void k_s_gemm(
    const bf16* __restrict__ QK, const float* __restrict__ adj,
    bf16* __restrict__ S, float* __restrict__ denom)
{
    const int b = blockIdx.y;
    int t = blockIdx.x, i = 0;
    while (t >= 16 - i) { t -= 16 - i; ++i; }   // triangular decode, i<=j
    const int j = i + t;
    const int rowI = i * 128, rowJ = j * 128;
    const bf16* Qb = QK + (size_t)b * Nn * Dd;
    GEMM_PROLOGUE();
    gemm_bt_core(Qb + (size_t)rowI * Dd, Qb + (size_t)rowJ * Dd,
                 Dd, Dd, Dd, As, Bs, acc);
    const float scale = 0.044194173824159216f;  // 1/sqrt(512)

    const int tid  = threadIdx.x;
    const int lane = tid & 63;
    const int wave = tid >> 6;
    const int wm = (wave >> 1) << 6;
    const int wn = (wave & 1) << 6;
    const int cq = lane >> 4;
    const int cl = lane & 15;
    float* tls = (float*)smem;       // [64][132]
    const int chunk = tid & 15;
    const int rbase = tid >> 4;

    auto store_side = [&](int blockRow, int blockCol, bool trans) {
#pragma unroll
        for (int ph = 0; ph < 2; ++ph) {
            __syncthreads();
            if (!trans) {
                if ((wave >> 1) == ph) {
#pragma unroll
                    for (int mi = 0; mi < 4; ++mi)
#pragma unroll
                        for (int ni = 0; ni < 4; ++ni)
#pragma unroll
                            for (int r = 0; r < 4; ++r)
                                tls[(mi * 16 + cq * 4 + r) * 132 + wn + ni * 16 + cl]
                                    = acc[mi][ni][r];
                }
            } else {
                if ((wave & 1) == ph) {
#pragma unroll
                    for (int mi = 0; mi < 4; ++mi)
#pragma unroll
                        for (int ni = 0; ni < 4; ++ni)
#pragma unroll
                            for (int r = 0; r < 4; ++r)
                                tls[(ni * 16 + cl) * 132 + wm + mi * 16 + cq * 4 + r]
                                    = acc[mi][ni][r];
                }
            }
            __syncthreads();
#pragma unroll
            for (int rr = 0; rr < 4; ++rr) {
                int lr = rr * 16 + rbase;
                f32x4 a = *(const f32x4*)&tls[lr * 132 + chunk * 8];
                f32x4 c4 = *(const f32x4*)&tls[lr * 132 + chunk * 8 + 4];
                float v[8] = {a[0], a[1], a[2], a[3], c4[0], c4[1], c4[2], c4[3]};
                int gRow = blockRow + ph * 64 + lr;
                size_t base = ((size_t)b * Nn + gRow) * Nn + blockCol + chunk * 8;
                float4 a0 = *(const float4*)(adj + base);
                float4 a1 = *(const float4*)(adj + base + 4);
                float aa[8] = {a0.x, a0.y, a0.z, a0.w, a1.x, a1.y, a1.z, a1.w};
                bf16x8 o;
                float ds = 0.f;
#pragma unroll
                for (int jj = 0; jj < 8; ++jj) {
                    float s = v[jj] * scale * aa[jj];
                    bf16 sb = to_bf16(s);
                    o[jj] = sb;
                    ds += (float)sb;
                }
                *(bf16x8*)(S + base) = o;
#pragma unroll
                for (int off = 8; off > 0; off >>= 1) ds += __shfl_xor(ds, off, 16);
                if ((tid & 15) == 0) atomicAdd(&denom[b * Nn + gRow], ds);
            }
        }
    };
    store_side(rowI, rowJ, false);
    if (i != j) store_side(rowJ, rowI, true);
}

// ---------------- K5: h = (S @ xgT^T) / (denom + 1e-6) [gemm8] ----------------
// 256 blocks: batch = id&7 (one batch per XCD under round-robin dispatch ->
// S[b] + xgT[b] panels stay in one XCD's L2).
__global__ __launch_bounds__(512) void k_h_gemm8(
    const bf16* __restrict__ S, const bf16* __restrict__ xgT,
    const float* __restrict__ denom, bf16* __restrict__ h)
{
    extern __shared__ __align__(16) char smem[];
    const int id  = blockIdx.x;          // 0..255
    const int b   = id & 7;
    const int pos = id >> 3;             // 0..31
    const int blockRow = (pos >> 2) * 256;
    const int blockCol = (pos & 3) * 128;
    f32x4 acc[4][4];
#pragma unroll
    for (int mi = 0; mi < 4; ++mi)
#pragma unroll
        for (int ni = 0; ni < 4; ++ni) acc[mi][ni] = (f32x4){0.f, 0.f, 0.f, 0.f};
    gemm_bt8_core(S + ((size_t)b * Nn + blockRow) * Nn,
                  xgT + ((size_t)b * Dd + blockCol) * Nn,
                  Nn, Nn, Nn, smem, acc);
    epilogue_rt8(acc, smem, [&](int lr, int lc, float* v) {
        int gRow = blockRow + lr;
        float inv = 1.0f / (denom[b * Nn + gRow] + 1e-6f);
        bf16x8 o;
#pragma unroll
        for (int j = 0; j < 8; ++j) o[j] = to_bf16(v[j] * inv);
        *(bf16x8*)(h + ((size_t)b * Nn + gRow) * Dd + blockCol + lc) = o;
    });
}

// -------- K6: out = relu(h @ Wl^T + bl + xg @ Wr^T) [gemm8] --------
__global__ __launch_bounds__(512) void k_out_gemm8(
    const bf16* __restrict__ h, const bf16* __restrict__ xg,
    const bf16* __restrict__ Wlb, const bf16* __restrict__ Wrb,
    const float* __restrict__ bl, float* __restrict__ out)
{
    extern __shared__ __align__(16) char smem[];
    const int blockRow = blockIdx.y * 256;   // 0..16383
    const int blockCol = blockIdx.x * 128;   // 0..511
    f32x4 acc[4][4];
#pragma unroll
    for (int mi = 0; mi < 4; ++mi)
#pragma unroll
        for (int ni = 0; ni < 4; ++ni) acc[mi][ni] = (f32x4){0.f, 0.f, 0.f, 0.f};
    gemm_bt8_core(h  + (size_t)blockRow * Dd, Wlb + (size_t)blockCol * Dd,
                  Dd, Dd, Dd, smem, acc);
    gemm_bt8_core(xg + (size_t)blockRow * Dd, Wrb + (size_t)blockCol * Dd,
                  Dd, Dd, Dd, smem, acc);
    epilogue_rt8(acc, smem, [&](int lr, int lc, float* v) {
        int c = blockCol + lc;
        float4 b0 = *(const float4*)(bl + c);
        float4 b1 = *(const float4*)(bl + c + 4);
        float bb[8] = {b0.x, b0.y, b0.z, b0.w, b1.x, b1.y, b1.z, b1.w};
        float4 o0, o1;
        o0.x = fmaxf(v[0] + bb[0], 0.f); o0.y = fmaxf(v[1] + bb[1], 0.f);
        o0.z = fmaxf(v[2] + bb[2], 0.f); o0.w = fmaxf(v[3] + bb[3], 0.f);
        o1.x = fmaxf(v[4] + bb[4], 0.f); o1.y = fmaxf(v[5] + bb[5], 0.f);
        o1.z = fmaxf(v[6] + bb[6], 0.f); o1.w = fmaxf(v[7] + bb[7], 0.f);
        float* p = out + (size_t)(blockRow + lr) * Dd + c;
        *(float4*)p = o0;
        *(float4*)(p + 4) = o1;
    });
}

extern "C" void kernel_launch(void* const* d_in, const int* in_sizes, int n_in,
                              void* d_out, int out_size, void* d_ws, size_t ws_size,
                              hipStream_t stream) {
    const float* x   = (const float*)d_in[0];
    const float* adj = (const float*)d_in[1];
    const float* Wqk = (const float*)d_in[2];
    const float* bqk = (const float*)d_in[3];
    const float* Wl  = (const float*)d_in[4];
    const float* bl  = (const float*)d_in[5];
    const float* Wr  = (const float*)d_in[6];
    const float* Wd  = (const float*)d_in[7];
    const float* bd  = (const float*)d_in[8];
    float* out = (float*)d_out;

    char* ws = (char*)d_ws;
    bf16* xg   = (bf16*)ws;  ws += (size_t)Bb * Nn * Dd * 2;   // 16.78 MB
    bf16* xgT  = (bf16*)ws;  ws += (size_t)Bb * Dd * Nn * 2;   // 16.78 MB
    bf16* QK   = (bf16*)ws;  ws += (size_t)Bb * Nn * Dd * 2;   // 16.78 MB
    bf16* S    = (bf16*)ws;  ws += (size_t)Bb * Nn * Nn * 2;   // 67.1 MB
    bf16* Wqkb = (bf16*)ws;  ws += (size_t)Dd * Dd * 2;
    bf16* Wlb  = (bf16*)ws;  ws += (size_t)Dd * Dd * 2;
    bf16* Wrb  = (bf16*)ws;  ws += (size_t)Dd * Dd * 2;
    float* denom = (float*)ws; ws += (size_t)Bb * Nn * 4;
    bf16* h = QK;   // QK dead after K4; alias h over it

    static bool attr_done = false;
    if (!attr_done) {
        hipFuncSetAttribute((const void*)k_qk_gemm8,
                            hipFuncAttributeMaxDynamicSharedMemorySize, SMEM8_BYTES);
        hipFuncSetAttribute((const void*)k_h_gemm8,
                            hipFuncAttributeMaxDynamicSharedMemorySize, SMEM8_BYTES);
        hipFuncSetAttribute((const void*)k_out_gemm8,
                            hipFuncAttributeMaxDynamicSharedMemorySize, SMEM8_BYTES);
        attr_done = true;
    }

    hipMemsetAsync(denom, 0, (size_t)Bb * Nn * sizeof(float), stream);
    k_castw<<<dim3(1024), 256, 0, stream>>>(Wqk, Wl, Wr, Wqkb, Wlb, Wrb);
    k_gate<<<dim3(Bb * Nn), 256, 0, stream>>>(x, adj, Wd, bd, xg);
    k_transpose<<<dim3(Dd / 64, Nn / 64, Bb), 256, 0, stream>>>(xg, xgT);
    k_qk_gemm8<<<dim3(Dd / 128, (Bb * Nn) / 256), 512, SMEM8_BYTES, stream>>>(xg, Wqkb, bqk, QK);
    k_s_gemm<<<dim3(136, Bb), 256, 0, stream>>>(QK, adj, S, denom);
    k_h_gemm8<<<dim3(256), 512, SMEM8_BYTES, stream>>>(S, xgT, denom, h);
    k_out_gemm8<<<dim3(Dd / 128, (Bb * Nn) / 256), 512, SMEM8_BYTES, stream>>>(h, xg, Wlb, Wrb, bl, out);
}